// Round 5
// baseline (287.482 us; speedup 1.0000x reference)
//
#include <hip/hip_runtime.h>
#include <hip/hip_bf16.h>

#define Dc   192
#define D2c  384
#define NYc  2304   // 48*48

// 1/sqrt(192) * log2(e): folded into wq weights+bias so QK^T scores are in
// log2 domain and softmax uses raw v_exp_f32 (= 2^x).
#define QSCALE 0.1041175462f

typedef __attribute__((ext_vector_type(8))) short short8;
typedef __attribute__((ext_vector_type(4))) float f32x4;

__device__ __forceinline__ unsigned short f2bf(float f) {
    unsigned int u = __float_as_uint(f);
    u += 0x7FFFu + ((u >> 16) & 1u);   // RNE
    return (unsigned short)(u >> 16);
}
__device__ __forceinline__ float fexp2(float x) {
    float r; asm("v_exp_f32 %0, %1" : "=v"(r) : "v"(x)); return r;
}
__device__ __forceinline__ unsigned cvtpk(float lo, float hi) {
    unsigned r; asm("v_cvt_pk_bf16_f32 %0, %1, %2" : "=v"(r) : "v"(lo), "v"(hi));
    return r;
}
// XCD-chunked bijective swizzle (requires nwg % 8 == 0)
__device__ __forceinline__ int swz8(int bid, int nwg) {
    return (bid & 7) * (nwg >> 3) + (bid >> 3);
}

// ---------------------------------------------------------------------------
// pe2d tables: peY[c][p] (384x48), peS[c][p] (192x48)
// ---------------------------------------------------------------------------
__global__ __launch_bounds__(256)
void build_pe_kernel(float* __restrict__ peY, float* __restrict__ peS) {
    int idx = blockIdx.x * 256 + threadIdx.x;    // 27648 total
    int c, p, C; float* dst; int off;
    if (idx < 18432) { c = idx / 48; p = idx % 48; C = 384; dst = peY; off = idx; }
    else { int k = idx - 18432; c = k / 48; p = k % 48; C = 192; dst = peS; off = k; }
    int dh = C >> 1;
    int i = ((c < dh) ? c : c - dh) >> 1;
    float divv = expf((float)(2 * i) * (-9.210340371976184f / (float)dh));
    float ang = (float)p * divv;
    dst[off] = (c & 1) ? cosf(ang) : sinf(ang);
}

// PE add + LDS-tiled transpose to token-major bf16 (y and s; s keeps fp32 ch-major)
// grid 648: [0,432) = y (b2 x 6ct x 36nt), [432,648) = s (b2 x 3ct x 36nt)
__global__ __launch_bounds__(256)
void prep_pe_kernel(const float* __restrict__ y, const float* __restrict__ s,
                    const float* __restrict__ peY, const float* __restrict__ peS,
                    unsigned short* __restrict__ ytok, unsigned short* __restrict__ stok,
                    float* __restrict__ sch) {
    __shared__ unsigned short T[64][66];
    int bid = blockIdx.x;
    int b, ct, nt, C; const float* in; const float* pe; unsigned short* outp; bool isS;
    if (bid < 432) { isS = false; b = bid / 216; int r = bid % 216; ct = r / 36; nt = r % 36;
                     in = y; pe = peY; outp = ytok; C = 384; }
    else { int l = bid - 432; isS = true; b = l / 108; int r = l % 108; ct = r / 36; nt = r % 36;
           in = s; pe = peS; outp = stok; C = 192; }
    int t = threadIdx.x;
    int nl = t & 63;
    int n = nt * 64 + nl;
    int pos_x = n % 48, pos_y = n / 48;
    #pragma unroll
    for (int i = 0; i < 16; ++i) {
        int cl = (t >> 6) + 4 * i;
        int c = ct * 64 + cl;
        int pos = (c < (C >> 1)) ? pos_x : pos_y;
        long gi = (long)b * C * NYc + (long)c * NYc + n;
        float v = in[gi] + pe[c * 48 + pos];
        if (isS) sch[gi] = v;
        T[nl][cl] = f2bf(v);
    }
    __syncthreads();
    #pragma unroll
    for (int i = 0; i < 8; ++i) {
        int nl2 = (t >> 5) + 8 * i;
        int cp  = t & 31;
        unsigned u = (unsigned)T[nl2][2 * cp] | ((unsigned)T[nl2][2 * cp + 1] << 16);
        long row = (long)b * NYc + nt * 64 + nl2;
        *(unsigned*)(outp + row * C + ct * 64 + 2 * cp) = u;
    }
}

// weight conversions: seven 1x1 mats (wq pre-scaled) + qk bias + up_w transpose
__global__ __launch_bounds__(256)
void prep_w_kernel(const float* __restrict__ w0, const float* __restrict__ w1,
                   const float* __restrict__ w2, const float* __restrict__ w3,
                   const float* __restrict__ w4, const float* __restrict__ w5,
                   const float* __restrict__ w6, unsigned short* __restrict__ dst,
                   const float* __restrict__ wq_b, const float* __restrict__ wk_b,
                   float* __restrict__ qkb,
                   const float* __restrict__ upw, unsigned short* __restrict__ upwt) {
    int idx = blockIdx.x * 256 + threadIdx.x;    // 1953792 total
    if (idx < 626688) {
        if (idx < 768)
            qkb[idx] = (idx < 384) ? wq_b[idx] * QSCALE : wk_b[idx - 384];
        const float* src; int off; float scl = 1.0f;
        if      (idx < 147456) { src = w0; off = idx; }
        else if (idx < 294912) { src = w1; off = idx - 147456; scl = QSCALE; }
        else if (idx < 442368) { src = w2; off = idx - 294912; }
        else if (idx < 479232) { src = w3; off = idx - 442368; }
        else if (idx < 516096) { src = w4; off = idx - 479232; }
        else if (idx < 552960) { src = w5; off = idx - 516096; }
        else                   { src = w6; off = idx - 552960; }
        dst[idx] = f2bf(src[off] * scl);
    } else {
        int k = idx - 626688;                    // up_w: [O][tap*384+c]
        int o = k / 3456; int r = k % 3456;
        int tap = r / 384;  int c = r % 384;
        upwt[k] = f2bf(upw[((long)o * 384 + c) * 9 + tap]);
    }
}

// ---------------------------------------------------------------------------
// Fused multi-segment bf16 MFMA GEMM. 64x64 tile, 4 waves (32x32 each), BK=64.
// D[m][n] = sum_k A'[m][k] * B'[n][k]; A',B' row-major [free][k] bf16.
// Segment flags: 1=im2col A, 2=BN+ReLU, 4=f32 out, 8=ch-major out (batch-wrap
// on n; bias axis m), 16=sigmoid-gate (*smul).
// ---------------------------------------------------------------------------
struct Seg {
    const unsigned short* A; const unsigned short* B;
    int aP, bP, K, nT, blkOff, flags;
    const float *bias, *bng, *bnb;
    char* out; int oPitch; long oBatch;
};

template<int NSEG>
__global__ __launch_bounds__(256)
void fused_gemm(Seg s0, Seg s1, Seg s2, const float* __restrict__ smul)
{
    int bid = swz8(blockIdx.x, gridDim.x);
    Seg sg = s0;
    if (NSEG > 1 && bid >= s1.blkOff) sg = s1;
    if (NSEG > 2 && bid >= s2.blkOff) sg = s2;
    int local = bid - sg.blkOff;
    int mt = local / sg.nT, nt = local - mt * sg.nT;
    int m0 = mt * 64, n0 = nt * 64;

    __shared__ __align__(16) unsigned short As[64][72];
    __shared__ __align__(16) unsigned short Bs[64][72];

    int t = threadIdx.x, lane = t & 63, w = t >> 6;
    int lr = lane & 15, lg = lane >> 4;
    int wm = (w >> 1) * 32, wn = (w & 1) * 32;

    f32x4 acc[2][2];
    #pragma unroll
    for (int i = 0; i < 2; ++i)
        #pragma unroll
        for (int j = 0; j < 2; ++j)
            acc[i][j] = (f32x4){0.f, 0.f, 0.f, 0.f};

    uint4 ra[2], rb[2];
    bool im2col = (sg.flags & 1) != 0;

    auto load = [&](int k0) {
        #pragma unroll
        for (int i = 0; i < 2; ++i) {
            int idx = t + i * 256, row = idx >> 3, sl = idx & 7;
            if (im2col) {
                int tok = m0 + row;
                int bb = tok >= NYc;
                int n = tok - bb * NYc;
                int tap = k0 / 384;
                int rem = k0 - tap * 384 + sl * 8;
                int py = n / 48 + tap / 3 - 1;
                int px = n % 48 + tap % 3 - 1;
                ra[i] = (py >= 0 && py < 48 && px >= 0 && px < 48)
                    ? *(const uint4*)(sg.A + ((long)bb * NYc + py * 48 + px) * sg.aP + rem)
                    : make_uint4(0, 0, 0, 0);
            } else {
                ra[i] = *(const uint4*)(sg.A + (long)(m0 + row) * sg.aP + k0 + sl * 8);
            }
            rb[i] = *(const uint4*)(sg.B + (long)(n0 + row) * sg.bP + k0 + sl * 8);
        }
    };
    auto store = [&]() {
        #pragma unroll
        for (int i = 0; i < 2; ++i) {
            int idx = t + i * 256;
            *(uint4*)&As[idx >> 3][(idx & 7) * 8] = ra[i];
            *(uint4*)&Bs[idx >> 3][(idx & 7) * 8] = rb[i];
        }
    };

    load(0); store(); __syncthreads();
    int NT = sg.K >> 6;
    for (int tt = 0; tt < NT; ++tt) {
        if (tt + 1 < NT) load((tt + 1) << 6);    // issue-early prefetch
        #pragma unroll
        for (int kk = 0; kk < 2; ++kk) {
            short8 a0 = *(const short8*)&As[wm + lr][kk * 32 + lg * 8];
            short8 a1 = *(const short8*)&As[wm + 16 + lr][kk * 32 + lg * 8];
            short8 b0 = *(const short8*)&Bs[wn + lr][kk * 32 + lg * 8];
            short8 b1 = *(const short8*)&Bs[wn + 16 + lr][kk * 32 + lg * 8];
            acc[0][0] = __builtin_amdgcn_mfma_f32_16x16x32_bf16(a0, b0, acc[0][0], 0, 0, 0);
            acc[0][1] = __builtin_amdgcn_mfma_f32_16x16x32_bf16(a0, b1, acc[0][1], 0, 0, 0);
            acc[1][0] = __builtin_amdgcn_mfma_f32_16x16x32_bf16(a1, b0, acc[1][0], 0, 0, 0);
            acc[1][1] = __builtin_amdgcn_mfma_f32_16x16x32_bf16(a1, b1, acc[1][1], 0, 0, 0);
        }
        __syncthreads();
        if (tt + 1 < NT) { store(); __syncthreads(); }
    }

    #pragma unroll
    for (int i = 0; i < 2; ++i)
    #pragma unroll
    for (int j = 0; j < 2; ++j)
    #pragma unroll
    for (int r = 0; r < 4; ++r) {
        int gm = m0 + wm + i * 16 + lg * 4 + r;
        int gn = n0 + wn + j * 16 + lr;
        int ch = (sg.flags & 8) ? gm : gn;
        float v = acc[i][j][r] + sg.bias[ch];
        if (sg.flags & 2)
            v = fmaxf(fmaf(v, sg.bng[ch], sg.bnb[ch]), 0.f);
        long o; int b = 0, tok = gn;
        if (sg.flags & 8) {
            b = gn >= NYc; tok = gn - b * NYc;
            o = (long)b * sg.oBatch + (long)gm * sg.oPitch + tok;
        } else {
            o = (long)gm * sg.oPitch + gn;
        }
        if (sg.flags & 16) {
            v = fmaf(v, sg.bng[ch], sg.bnb[ch]);
            v = 1.f / (1.f + __expf(-v));
            v *= smul[(long)b * 442368 + (long)gm * NYc + tok];
        }
        if (sg.flags & 4) ((float*)sg.out)[o] = v;
        else              ((unsigned short*)sg.out)[o] = f2bf(v);
    }
}

// ---------------------------------------------------------------------------
// Fused MFMA flash attention (round-3 structure + XCD swizzle on flat grid).
// ---------------------------------------------------------------------------
__global__ __launch_bounds__(512)
void attn_kernel(const unsigned short* __restrict__ QK,
                 const unsigned short* __restrict__ Vc,
                 unsigned short* __restrict__ Zt)
{
    int nid = swz8(blockIdx.x, 576);
    int qb = nid % 36;                   // 0..35
    int bh = nid / 36;                   // 0..15
    int b = bh >> 3, h = bh & 7;
    const unsigned short* Qg = QK + (long)b * NYc * 768 + h * 48;
    const unsigned short* Kg = Qg + 384;
    const unsigned short* Vg = Vc + ((long)b * Dc + h * 24) * NYc;
    unsigned short*       Z  = Zt + (long)b * NYc * Dc + h * 24;

    __shared__ __align__(16) unsigned short Ks_[128][72];
    __shared__ __align__(16) unsigned short Vs_[32][136];
    __shared__ __align__(16) unsigned int   Ps_[8][16][36];

    int t = threadIdx.x, lane = t & 63, w = t >> 6;
    int lr = lane & 15, lg = lane >> 4;
    int tm = w >> 1, hf = w & 1;
    int q0 = qb * 64;

    short8 z8 = {0, 0, 0, 0, 0, 0, 0, 0};
    const unsigned short* qrow = Qg + (long)(q0 + tm * 16 + lr) * 768;
    short8 bq0 = *(const short8*)(qrow + lg * 8);
    short8 bq1 = (lg < 2) ? *(const short8*)(qrow + 32 + lg * 8) : z8;

    float m_run = -1e30f, l_run = 0.f;
    f32x4 O0 = {0.f, 0.f, 0.f, 0.f}, O1 = {0.f, 0.f, 0.f, 0.f};

    for (int kt = 0; kt < 18; ++kt) {
        long k0 = kt * 128;
        #pragma unroll
        for (int i = 0; i < 2; ++i) {
            int idx = t + i * 512;
            int row = idx >> 3, sl = idx & 7;
            uint4 v = make_uint4(0, 0, 0, 0);
            if (sl < 6) v = *(const uint4*)(Kg + (k0 + row) * 768 + sl * 8);
            *(uint4*)&Ks_[row][sl * 8] = v;
        }
        if (t < 384) {
            int row = t >> 4, sl = t & 15;
            *(uint4*)&Vs_[row][sl * 8] =
                *(const uint4*)(Vg + (long)row * NYc + k0 + sl * 8);
        }
        __syncthreads();

        f32x4 sS[4];
        #pragma unroll
        for (int ks = 0; ks < 4; ++ks) {
            short8 ak0 = *(const short8*)&Ks_[hf * 64 + ks * 16 + lr][lg * 8];
            short8 ak1 = *(const short8*)&Ks_[hf * 64 + ks * 16 + lr][32 + lg * 8];
            f32x4 c = {0.f, 0.f, 0.f, 0.f};
            c = __builtin_amdgcn_mfma_f32_16x16x32_bf16(ak0, bq0, c, 0, 0, 0);
            c = __builtin_amdgcn_mfma_f32_16x16x32_bf16(ak1, bq1, c, 0, 0, 0);
            sS[ks] = c;
        }

        float tmax = -1e30f;
        #pragma unroll
        for (int ks = 0; ks < 4; ++ks)
            #pragma unroll
            for (int r = 0; r < 4; ++r) tmax = fmaxf(tmax, sS[ks][r]);
        tmax = fmaxf(tmax, __shfl_xor(tmax, 16));
        tmax = fmaxf(tmax, __shfl_xor(tmax, 32));

        if (__any(tmax > m_run + 10.f)) {
            float mn = fmaxf(m_run, tmax);
            float al = fexp2(m_run - mn);
            m_run = mn;
            l_run *= al;
            #pragma unroll
            for (int rr = 0; rr < 4; ++rr) {
                float arr = __shfl(al, (lane & 48) | (lg * 4 + rr));
                O0[rr] *= arr; O1[rr] *= arr;
            }
        }

        float psum = 0.f;
        #pragma unroll
        for (int ks = 0; ks < 4; ++ks) {
            float p0 = fexp2(sS[ks][0] - m_run);
            float p1 = fexp2(sS[ks][1] - m_run);
            float p2 = fexp2(sS[ks][2] - m_run);
            float p3 = fexp2(sS[ks][3] - m_run);
            psum += (p0 + p1) + (p2 + p3);
            Ps_[w][lr][8 * ks + 2 * lg]     = cvtpk(p0, p1);
            Ps_[w][lr][8 * ks + 2 * lg + 1] = cvtpk(p2, p3);
        }
        psum += __shfl_xor(psum, 16);
        psum += __shfl_xor(psum, 32);
        l_run += psum;

        short8 ap0 = *(const short8*)&Ps_[w][lr][4 * lg];
        short8 ap1 = *(const short8*)&Ps_[w][lr][16 + 4 * lg];
        short8 bv00 = *(const short8*)&Vs_[lr][hf * 64 + lg * 8];
        short8 bv01 = *(const short8*)&Vs_[lr][hf * 64 + 32 + lg * 8];
        short8 bv10 = *(const short8*)&Vs_[16 + lr][hf * 64 + lg * 8];
        short8 bv11 = *(const short8*)&Vs_[16 + lr][hf * 64 + 32 + lg * 8];
        O0 = __builtin_amdgcn_mfma_f32_16x16x32_bf16(ap0, bv00, O0, 0, 0, 0);
        O0 = __builtin_amdgcn_mfma_f32_16x16x32_bf16(ap1, bv01, O0, 0, 0, 0);
        O1 = __builtin_amdgcn_mfma_f32_16x16x32_bf16(ap0, bv10, O1, 0, 0, 0);
        O1 = __builtin_amdgcn_mfma_f32_16x16x32_bf16(ap1, bv11, O1, 0, 0, 0);
        __syncthreads();
    }

    float* Cf = (float*)&Ps_[0][0][0];
    float* T = Cf + tm * 576;
    if (hf == 1) {
        #pragma unroll
        for (int j = 0; j < 4; ++j) {
            T[lane * 8 + j]     = O0[j];
            T[lane * 8 + 4 + j] = O1[j];
        }
        if (lane < 16) { T[512 + lane] = m_run; T[528 + lane] = l_run; }
    }
    __syncthreads();
    if (hf == 0) {
        float mB = T[512 + lr], lB = T[528 + lr];
        float mS = fmaxf(m_run, mB);
        float aA = fexp2(m_run - mS), aB = fexp2(mB - mS);
        float invl = 1.f / (l_run * aA + lB * aB);
        float fA = aA * invl, fB = aB * invl;
        #pragma unroll
        for (int rr = 0; rr < 4; ++rr) {
            int src = (lane & 48) | (lg * 4 + rr);
            float gA = __shfl(fA, src), gB = __shfl(fB, src);
            int n = q0 + tm * 16 + lg * 4 + rr;
            unsigned short* zr = Z + (long)n * Dc;
            float z0 = O0[rr] * gA + T[lane * 8 + rr] * gB;
            zr[lr] = f2bf(z0);
            if (lr < 8) {
                float z1 = O1[rr] * gA + T[lane * 8 + 4 + rr] * gB;
                zr[16 + lr] = f2bf(z1);
            }
        }
    }
}

// ---------------------------------------------------------------------------
extern "C" void kernel_launch(void* const* d_in, const int* in_sizes, int n_in,
                              void* d_out, int out_size, void* d_ws, size_t ws_size,
                              hipStream_t stream) {
    const float* y       = (const float*)d_in[0];
    const float* s       = (const float*)d_in[1];
    const float* wq_w    = (const float*)d_in[2];
    const float* wq_b    = (const float*)d_in[3];
    const float* wk_w    = (const float*)d_in[4];
    const float* wk_b    = (const float*)d_in[5];
    const float* wv_w    = (const float*)d_in[6];
    const float* wv_b    = (const float*)d_in[7];
    const float* conv1_w = (const float*)d_in[8];
    const float* conv1_b = (const float*)d_in[9];
    const float* bn1_g   = (const float*)d_in[10];
    const float* bn1_b   = (const float*)d_in[11];
    const float* conv2_w = (const float*)d_in[12];
    const float* conv2_b = (const float*)d_in[13];
    const float* bn2_g   = (const float*)d_in[14];
    const float* bn2_b   = (const float*)d_in[15];
    const float* up_w    = (const float*)d_in[16];
    const float* up_b    = (const float*)d_in[17];
    const float* conv3_w = (const float*)d_in[18];
    const float* conv3_b = (const float*)d_in[19];
    const float* bn3_g   = (const float*)d_in[20];
    const float* bn3_b   = (const float*)d_in[21];
    const float* sig_w   = (const float*)d_in[22];
    const float* sig_b   = (const float*)d_in[23];
    const float* bnsig_g = (const float*)d_in[24];
    const float* bnsig_b = (const float*)d_in[25];

    unsigned short* wsp   = (unsigned short*)d_ws;
    unsigned short* wcvt  = wsp;                     // 626688
    unsigned short* upwt  = wcvt + 626688;           // 1327104
    unsigned short* y_pe  = upwt + 1327104;          // 1769472  [4608][384]
    unsigned short* s_pe  = y_pe + 1769472;          //  884736  [4608][192]
    unsigned short* y_c1  = s_pe + 884736;           // 1769472
    unsigned short* s_c2  = y_c1 + 1769472;          //  884736
    unsigned short* y_up  = s_c2 + 884736;           // 1769472
    unsigned short* QKtok = y_up + 1769472;          // 3538944  [4608][768]
    unsigned short* Vch   = QKtok + 3538944;         //  884736  [b][192][2304]
    unsigned short* Ztok  = Vch + 884736;            //  884736  [4608][192]
    float*          s_ch  = (float*)(Ztok + 884736); //  884736 fp32
    float*          qkb   = s_ch + 884736;           //  768 fp32
    float*          peY   = qkb + 768;               //  18432 fp32
    float*          peS   = peY + 18432;             //  9216 fp32

    const unsigned short* conv1wb = wcvt;
    const unsigned short* wqkb    = wcvt + 147456;   // wq||wk, 768 x 384
    const unsigned short* conv2wb = wcvt + 442368;
    const unsigned short* wvb     = wcvt + 479232;
    const unsigned short* sigwb   = wcvt + 516096;
    const unsigned short* conv3wb = wcvt + 552960;

    build_pe_kernel<<<108, 256, 0, stream>>>(peY, peS);
    prep_w_kernel<<<7632, 256, 0, stream>>>(conv1_w, wq_w, wk_w, conv2_w,
                                            wv_w, sig_w, conv3_w, wcvt,
                                            wq_b, wk_b, qkb, up_w, upwt);
    prep_pe_kernel<<<648, 256, 0, stream>>>(y, s, peY, peS, y_pe, s_pe, s_ch);

    Seg sz = {};   // unused slot filler

    // G1: conv1 (432 blk) + conv2 (216) + up (432)  -> 1080 blocks
    {
        Seg a = { y_pe, conv1wb, D2c, D2c, D2c, 6, 0, 2,
                  conv1_b, bn1_g, bn1_b, (char*)y_c1, D2c, 0 };
        Seg b = { s_pe, conv2wb, Dc, Dc, Dc, 3, 432, 2,
                  conv2_b, bn2_g, bn2_b, (char*)s_c2, Dc, 0 };
        Seg c = { y_pe, upwt, D2c, 9 * D2c, 9 * D2c, 6, 648, 1,
                  up_b, nullptr, nullptr, (char*)y_up, D2c, 0 };
        fused_gemm<3><<<1080, 256, 0, stream>>>(a, b, c, nullptr);
    }
    // G2: QK (864) + conv3 (216) + V (216) -> 1296 blocks
    {
        Seg a = { y_c1, wqkb, D2c, D2c, D2c, 12, 0, 0,
                  qkb, nullptr, nullptr, (char*)QKtok, 768, 0 };
        Seg b = { conv3wb, y_up, D2c, D2c, D2c, 72, 864, 2 | 4 | 8,
                  conv3_b, bn3_g, bn3_b,
                  (char*)((float*)d_out + (long)Dc * NYc), NYc, 884736 };
        Seg c = { wvb, s_c2, Dc, Dc, Dc, 72, 1080, 8,
                  wv_b, nullptr, nullptr, (char*)Vch, NYc, 442368 };
        fused_gemm<3><<<1296, 256, 0, stream>>>(a, b, c, nullptr);
    }
    // attention
    attn_kernel<<<576, 512, 0, stream>>>(QKtok, Vch, Ztok);
    // G4: sigmoid gate (216 blocks)
    {
        Seg a = { sigwb, Ztok, Dc, Dc, Dc, 72, 0, 4 | 8 | 16,
                  sig_b, bnsig_g, bnsig_b, (char*)d_out, NYc, 884736 };
        fused_gemm<1><<<216, 256, 0, stream>>>(a, sz, sz, s_ch);
    }
}

// Round 6
// 198.488 us; speedup vs baseline: 1.4484x; 1.4484x over previous
//
#include <hip/hip_runtime.h>
#include <hip/hip_bf16.h>

#define Dc   192
#define D2c  384
#define NYc  2304   // 48*48

// 1/sqrt(192) * log2(e): folded into wq weights+bias so QK^T scores are in
// log2 domain and softmax uses raw v_exp_f32 (= 2^x).
#define QSCALE 0.1041175462f

typedef __attribute__((ext_vector_type(8))) short short8;
typedef __attribute__((ext_vector_type(4))) float f32x4;

__device__ __forceinline__ unsigned short f2bf(float f) {
    unsigned int u = __float_as_uint(f);
    u += 0x7FFFu + ((u >> 16) & 1u);   // RNE
    return (unsigned short)(u >> 16);
}
__device__ __forceinline__ float fexp2(float x) {
    float r; asm("v_exp_f32 %0, %1" : "=v"(r) : "v"(x)); return r;
}
__device__ __forceinline__ unsigned cvtpk(float lo, float hi) {
    unsigned r; asm("v_cvt_pk_bf16_f32 %0, %1, %2" : "=v"(r) : "v"(lo), "v"(hi));
    return r;
}
// XCD-chunked bijective swizzle (requires nwg % 8 == 0)
__device__ __forceinline__ int swz8(int bid, int nwg) {
    return (bid & 7) * (nwg >> 3) + (bid >> 3);
}

// ---------------------------------------------------------------------------
// pe2d tables: peY[c][p] (384x48), peS[c][p] (192x48)
// ---------------------------------------------------------------------------
__global__ __launch_bounds__(256)
void build_pe_kernel(float* __restrict__ peY, float* __restrict__ peS) {
    int idx = blockIdx.x * 256 + threadIdx.x;    // 27648 total
    int c, p, C; float* dst; int off;
    if (idx < 18432) { c = idx / 48; p = idx % 48; C = 384; dst = peY; off = idx; }
    else { int k = idx - 18432; c = k / 48; p = k % 48; C = 192; dst = peS; off = k; }
    int dh = C >> 1;
    int i = ((c < dh) ? c : c - dh) >> 1;
    float divv = expf((float)(2 * i) * (-9.210340371976184f / (float)dh));
    float ang = (float)p * divv;
    dst[off] = (c & 1) ? cosf(ang) : sinf(ang);
}

// PE add + LDS-tiled transpose to token-major bf16 (y and s; s keeps fp32 ch-major)
// grid 648: [0,432) = y (b2 x 6ct x 36nt), [432,648) = s (b2 x 3ct x 36nt)
__global__ __launch_bounds__(256)
void prep_pe_kernel(const float* __restrict__ y, const float* __restrict__ s,
                    const float* __restrict__ peY, const float* __restrict__ peS,
                    unsigned short* __restrict__ ytok, unsigned short* __restrict__ stok,
                    float* __restrict__ sch) {
    __shared__ unsigned short T[64][66];
    int bid = blockIdx.x;
    int b, ct, nt, C; const float* in; const float* pe; unsigned short* outp; bool isS;
    if (bid < 432) { isS = false; b = bid / 216; int r = bid % 216; ct = r / 36; nt = r % 36;
                     in = y; pe = peY; outp = ytok; C = 384; }
    else { int l = bid - 432; isS = true; b = l / 108; int r = l % 108; ct = r / 36; nt = r % 36;
           in = s; pe = peS; outp = stok; C = 192; }
    int t = threadIdx.x;
    int nl = t & 63;
    int n = nt * 64 + nl;
    int pos_x = n % 48, pos_y = n / 48;
    #pragma unroll
    for (int i = 0; i < 16; ++i) {
        int cl = (t >> 6) + 4 * i;
        int c = ct * 64 + cl;
        int pos = (c < (C >> 1)) ? pos_x : pos_y;
        long gi = (long)b * C * NYc + (long)c * NYc + n;
        float v = in[gi] + pe[c * 48 + pos];
        if (isS) sch[gi] = v;
        T[nl][cl] = f2bf(v);
    }
    __syncthreads();
    #pragma unroll
    for (int i = 0; i < 8; ++i) {
        int nl2 = (t >> 5) + 8 * i;
        int cp  = t & 31;
        unsigned u = (unsigned)T[nl2][2 * cp] | ((unsigned)T[nl2][2 * cp + 1] << 16);
        long row = (long)b * NYc + nt * 64 + nl2;
        *(unsigned*)(outp + row * C + ct * 64 + 2 * cp) = u;
    }
}

// weight conversions: seven 1x1 mats (wq pre-scaled) + qk bias + up_w transpose
__global__ __launch_bounds__(256)
void prep_w_kernel(const float* __restrict__ w0, const float* __restrict__ w1,
                   const float* __restrict__ w2, const float* __restrict__ w3,
                   const float* __restrict__ w4, const float* __restrict__ w5,
                   const float* __restrict__ w6, unsigned short* __restrict__ dst,
                   const float* __restrict__ wq_b, const float* __restrict__ wk_b,
                   float* __restrict__ qkb,
                   const float* __restrict__ upw, unsigned short* __restrict__ upwt) {
    int idx = blockIdx.x * 256 + threadIdx.x;    // 1953792 total
    if (idx < 626688) {
        if (idx < 768)
            qkb[idx] = (idx < 384) ? wq_b[idx] * QSCALE : wk_b[idx - 384];
        const float* src; int off; float scl = 1.0f;
        if      (idx < 147456) { src = w0; off = idx; }
        else if (idx < 294912) { src = w1; off = idx - 147456; scl = QSCALE; }
        else if (idx < 442368) { src = w2; off = idx - 294912; }
        else if (idx < 479232) { src = w3; off = idx - 442368; }
        else if (idx < 516096) { src = w4; off = idx - 479232; }
        else if (idx < 552960) { src = w5; off = idx - 516096; }
        else                   { src = w6; off = idx - 552960; }
        dst[idx] = f2bf(src[off] * scl);
    } else {
        int k = idx - 626688;                    // up_w: [O][tap*384+c]
        int o = k / 3456; int r = k % 3456;
        int tap = r / 384;  int c = r % 384;
        upwt[k] = f2bf(upw[((long)o * 384 + c) * 9 + tap]);
    }
}

// ---------------------------------------------------------------------------
// Fused multi-segment bf16 MFMA GEMM. 64x64 tile, 4 waves (32x32 each), BK=64.
// D[m][n] = sum_k A'[m][k] * B'[n][k]; A',B' row-major [free][k] bf16.
// Segment select on RAW blockIdx.x; XCD swizzle applied per-segment (every
// segment's blkOff and nBlk are multiples of 8 so blockIdx%8 -> XCD stays even).
// Segment flags: 1=im2col A, 2=BN+ReLU, 4=f32 out, 8=ch-major out (batch-wrap
// on n; bias axis m), 16=sigmoid-gate (*smul).
// ---------------------------------------------------------------------------
struct Seg {
    const unsigned short* A; const unsigned short* B;
    int aP, bP, K, nT, blkOff, nBlk, flags;
    const float *bias, *bng, *bnb;
    char* out; int oPitch; long oBatch;
};

template<int NSEG>
__global__ __launch_bounds__(256)
void fused_gemm(Seg s0, Seg s1, Seg s2, const float* __restrict__ smul)
{
    int raw = blockIdx.x;
    Seg sg = s0;
    if (NSEG > 1 && raw >= s1.blkOff) sg = s1;
    if (NSEG > 2 && raw >= s2.blkOff) sg = s2;
    int local = raw - sg.blkOff;
    local = (local & 7) * (sg.nBlk >> 3) + (local >> 3);   // per-segment XCD chunk
    int mt = local / sg.nT, nt = local - mt * sg.nT;
    int m0 = mt * 64, n0 = nt * 64;

    __shared__ __align__(16) unsigned short As[64][72];
    __shared__ __align__(16) unsigned short Bs[64][72];

    int t = threadIdx.x, lane = t & 63, w = t >> 6;
    int lr = lane & 15, lg = lane >> 4;
    int wm = (w >> 1) * 32, wn = (w & 1) * 32;

    f32x4 acc[2][2];
    #pragma unroll
    for (int i = 0; i < 2; ++i)
        #pragma unroll
        for (int j = 0; j < 2; ++j)
            acc[i][j] = (f32x4){0.f, 0.f, 0.f, 0.f};

    uint4 ra[2], rb[2];
    bool im2col = (sg.flags & 1) != 0;

    auto load = [&](int k0) {
        #pragma unroll
        for (int i = 0; i < 2; ++i) {
            int idx = t + i * 256, row = idx >> 3, sl = idx & 7;
            if (im2col) {
                int tok = m0 + row;
                int bb = tok >= NYc;
                int n = tok - bb * NYc;
                int tap = k0 / 384;
                int rem = k0 - tap * 384 + sl * 8;
                int py = n / 48 + tap / 3 - 1;
                int px = n % 48 + tap % 3 - 1;
                ra[i] = (py >= 0 && py < 48 && px >= 0 && px < 48)
                    ? *(const uint4*)(sg.A + ((long)bb * NYc + py * 48 + px) * sg.aP + rem)
                    : make_uint4(0, 0, 0, 0);
            } else {
                ra[i] = *(const uint4*)(sg.A + (long)(m0 + row) * sg.aP + k0 + sl * 8);
            }
            rb[i] = *(const uint4*)(sg.B + (long)(n0 + row) * sg.bP + k0 + sl * 8);
        }
    };
    auto store = [&]() {
        #pragma unroll
        for (int i = 0; i < 2; ++i) {
            int idx = t + i * 256;
            *(uint4*)&As[idx >> 3][(idx & 7) * 8] = ra[i];
            *(uint4*)&Bs[idx >> 3][(idx & 7) * 8] = rb[i];
        }
    };

    load(0); store(); __syncthreads();
    int NT = sg.K >> 6;
    for (int tt = 0; tt < NT; ++tt) {
        if (tt + 1 < NT) load((tt + 1) << 6);    // issue-early prefetch
        #pragma unroll
        for (int kk = 0; kk < 2; ++kk) {
            short8 a0 = *(const short8*)&As[wm + lr][kk * 32 + lg * 8];
            short8 a1 = *(const short8*)&As[wm + 16 + lr][kk * 32 + lg * 8];
            short8 b0 = *(const short8*)&Bs[wn + lr][kk * 32 + lg * 8];
            short8 b1 = *(const short8*)&Bs[wn + 16 + lr][kk * 32 + lg * 8];
            acc[0][0] = __builtin_amdgcn_mfma_f32_16x16x32_bf16(a0, b0, acc[0][0], 0, 0, 0);
            acc[0][1] = __builtin_amdgcn_mfma_f32_16x16x32_bf16(a0, b1, acc[0][1], 0, 0, 0);
            acc[1][0] = __builtin_amdgcn_mfma_f32_16x16x32_bf16(a1, b0, acc[1][0], 0, 0, 0);
            acc[1][1] = __builtin_amdgcn_mfma_f32_16x16x32_bf16(a1, b1, acc[1][1], 0, 0, 0);
        }
        __syncthreads();
        if (tt + 1 < NT) { store(); __syncthreads(); }
    }

    #pragma unroll
    for (int i = 0; i < 2; ++i)
    #pragma unroll
    for (int j = 0; j < 2; ++j)
    #pragma unroll
    for (int r = 0; r < 4; ++r) {
        int gm = m0 + wm + i * 16 + lg * 4 + r;
        int gn = n0 + wn + j * 16 + lr;
        int ch = (sg.flags & 8) ? gm : gn;
        float v = acc[i][j][r] + sg.bias[ch];
        if (sg.flags & 2)
            v = fmaxf(fmaf(v, sg.bng[ch], sg.bnb[ch]), 0.f);
        long o; int b = 0, tok = gn;
        if (sg.flags & 8) {
            b = gn >= NYc; tok = gn - b * NYc;
            o = (long)b * sg.oBatch + (long)gm * sg.oPitch + tok;
        } else {
            o = (long)gm * sg.oPitch + gn;
        }
        if (sg.flags & 16) {
            v = fmaf(v, sg.bng[ch], sg.bnb[ch]);
            v = 1.f / (1.f + __expf(-v));
            v *= smul[(long)b * 442368 + (long)gm * NYc + tok];
        }
        if (sg.flags & 4) ((float*)sg.out)[o] = v;
        else              ((unsigned short*)sg.out)[o] = f2bf(v);
    }
}

// ---------------------------------------------------------------------------
// Fused MFMA flash attention (round-3 structure + XCD swizzle on flat grid).
// ---------------------------------------------------------------------------
__global__ __launch_bounds__(512)
void attn_kernel(const unsigned short* __restrict__ QK,
                 const unsigned short* __restrict__ Vc,
                 unsigned short* __restrict__ Zt)
{
    int nid = swz8(blockIdx.x, 576);
    int qb = nid % 36;                   // 0..35
    int bh = nid / 36;                   // 0..15
    int b = bh >> 3, h = bh & 7;
    const unsigned short* Qg = QK + (long)b * NYc * 768 + h * 48;
    const unsigned short* Kg = Qg + 384;
    const unsigned short* Vg = Vc + ((long)b * Dc + h * 24) * NYc;
    unsigned short*       Z  = Zt + (long)b * NYc * Dc + h * 24;

    __shared__ __align__(16) unsigned short Ks_[128][72];
    __shared__ __align__(16) unsigned short Vs_[32][136];
    __shared__ __align__(16) unsigned int   Ps_[8][16][36];

    int t = threadIdx.x, lane = t & 63, w = t >> 6;
    int lr = lane & 15, lg = lane >> 4;
    int tm = w >> 1, hf = w & 1;
    int q0 = qb * 64;

    short8 z8 = {0, 0, 0, 0, 0, 0, 0, 0};
    const unsigned short* qrow = Qg + (long)(q0 + tm * 16 + lr) * 768;
    short8 bq0 = *(const short8*)(qrow + lg * 8);
    short8 bq1 = (lg < 2) ? *(const short8*)(qrow + 32 + lg * 8) : z8;

    float m_run = -1e30f, l_run = 0.f;
    f32x4 O0 = {0.f, 0.f, 0.f, 0.f}, O1 = {0.f, 0.f, 0.f, 0.f};

    for (int kt = 0; kt < 18; ++kt) {
        long k0 = kt * 128;
        #pragma unroll
        for (int i = 0; i < 2; ++i) {
            int idx = t + i * 512;
            int row = idx >> 3, sl = idx & 7;
            uint4 v = make_uint4(0, 0, 0, 0);
            if (sl < 6) v = *(const uint4*)(Kg + (k0 + row) * 768 + sl * 8);
            *(uint4*)&Ks_[row][sl * 8] = v;
        }
        if (t < 384) {
            int row = t >> 4, sl = t & 15;
            *(uint4*)&Vs_[row][sl * 8] =
                *(const uint4*)(Vg + (long)row * NYc + k0 + sl * 8);
        }
        __syncthreads();

        f32x4 sS[4];
        #pragma unroll
        for (int ks = 0; ks < 4; ++ks) {
            short8 ak0 = *(const short8*)&Ks_[hf * 64 + ks * 16 + lr][lg * 8];
            short8 ak1 = *(const short8*)&Ks_[hf * 64 + ks * 16 + lr][32 + lg * 8];
            f32x4 c = {0.f, 0.f, 0.f, 0.f};
            c = __builtin_amdgcn_mfma_f32_16x16x32_bf16(ak0, bq0, c, 0, 0, 0);
            c = __builtin_amdgcn_mfma_f32_16x16x32_bf16(ak1, bq1, c, 0, 0, 0);
            sS[ks] = c;
        }

        float tmax = -1e30f;
        #pragma unroll
        for (int ks = 0; ks < 4; ++ks)
            #pragma unroll
            for (int r = 0; r < 4; ++r) tmax = fmaxf(tmax, sS[ks][r]);
        tmax = fmaxf(tmax, __shfl_xor(tmax, 16));
        tmax = fmaxf(tmax, __shfl_xor(tmax, 32));

        if (__any(tmax > m_run + 10.f)) {
            float mn = fmaxf(m_run, tmax);
            float al = fexp2(m_run - mn);
            m_run = mn;
            l_run *= al;
            #pragma unroll
            for (int rr = 0; rr < 4; ++rr) {
                float arr = __shfl(al, (lane & 48) | (lg * 4 + rr));
                O0[rr] *= arr; O1[rr] *= arr;
            }
        }

        float psum = 0.f;
        #pragma unroll
        for (int ks = 0; ks < 4; ++ks) {
            float p0 = fexp2(sS[ks][0] - m_run);
            float p1 = fexp2(sS[ks][1] - m_run);
            float p2 = fexp2(sS[ks][2] - m_run);
            float p3 = fexp2(sS[ks][3] - m_run);
            psum += (p0 + p1) + (p2 + p3);
            Ps_[w][lr][8 * ks + 2 * lg]     = cvtpk(p0, p1);
            Ps_[w][lr][8 * ks + 2 * lg + 1] = cvtpk(p2, p3);
        }
        psum += __shfl_xor(psum, 16);
        psum += __shfl_xor(psum, 32);
        l_run += psum;

        short8 ap0 = *(const short8*)&Ps_[w][lr][4 * lg];
        short8 ap1 = *(const short8*)&Ps_[w][lr][16 + 4 * lg];
        short8 bv00 = *(const short8*)&Vs_[lr][hf * 64 + lg * 8];
        short8 bv01 = *(const short8*)&Vs_[lr][hf * 64 + 32 + lg * 8];
        short8 bv10 = *(const short8*)&Vs_[16 + lr][hf * 64 + lg * 8];
        short8 bv11 = *(const short8*)&Vs_[16 + lr][hf * 64 + 32 + lg * 8];
        O0 = __builtin_amdgcn_mfma_f32_16x16x32_bf16(ap0, bv00, O0, 0, 0, 0);
        O0 = __builtin_amdgcn_mfma_f32_16x16x32_bf16(ap1, bv01, O0, 0, 0, 0);
        O1 = __builtin_amdgcn_mfma_f32_16x16x32_bf16(ap0, bv10, O1, 0, 0, 0);
        O1 = __builtin_amdgcn_mfma_f32_16x16x32_bf16(ap1, bv11, O1, 0, 0, 0);
        __syncthreads();
    }

    float* Cf = (float*)&Ps_[0][0][0];
    float* T = Cf + tm * 576;
    if (hf == 1) {
        #pragma unroll
        for (int j = 0; j < 4; ++j) {
            T[lane * 8 + j]     = O0[j];
            T[lane * 8 + 4 + j] = O1[j];
        }
        if (lane < 16) { T[512 + lane] = m_run; T[528 + lane] = l_run; }
    }
    __syncthreads();
    if (hf == 0) {
        float mB = T[512 + lr], lB = T[528 + lr];
        float mS = fmaxf(m_run, mB);
        float aA = fexp2(m_run - mS), aB = fexp2(mB - mS);
        float invl = 1.f / (l_run * aA + lB * aB);
        float fA = aA * invl, fB = aB * invl;
        #pragma unroll
        for (int rr = 0; rr < 4; ++rr) {
            int src = (lane & 48) | (lg * 4 + rr);
            float gA = __shfl(fA, src), gB = __shfl(fB, src);
            int n = q0 + tm * 16 + lg * 4 + rr;
            unsigned short* zr = Z + (long)n * Dc;
            float z0 = O0[rr] * gA + T[lane * 8 + rr] * gB;
            zr[lr] = f2bf(z0);
            if (lr < 8) {
                float z1 = O1[rr] * gA + T[lane * 8 + 4 + rr] * gB;
                zr[16 + lr] = f2bf(z1);
            }
        }
    }
}

// ---------------------------------------------------------------------------
extern "C" void kernel_launch(void* const* d_in, const int* in_sizes, int n_in,
                              void* d_out, int out_size, void* d_ws, size_t ws_size,
                              hipStream_t stream) {
    const float* y       = (const float*)d_in[0];
    const float* s       = (const float*)d_in[1];
    const float* wq_w    = (const float*)d_in[2];
    const float* wq_b    = (const float*)d_in[3];
    const float* wk_w    = (const float*)d_in[4];
    const float* wk_b    = (const float*)d_in[5];
    const float* wv_w    = (const float*)d_in[6];
    const float* wv_b    = (const float*)d_in[7];
    const float* conv1_w = (const float*)d_in[8];
    const float* conv1_b = (const float*)d_in[9];
    const float* bn1_g   = (const float*)d_in[10];
    const float* bn1_b   = (const float*)d_in[11];
    const float* conv2_w = (const float*)d_in[12];
    const float* conv2_b = (const float*)d_in[13];
    const float* bn2_g   = (const float*)d_in[14];
    const float* bn2_b   = (const float*)d_in[15];
    const float* up_w    = (const float*)d_in[16];
    const float* up_b    = (const float*)d_in[17];
    const float* conv3_w = (const float*)d_in[18];
    const float* conv3_b = (const float*)d_in[19];
    const float* bn3_g   = (const float*)d_in[20];
    const float* bn3_b   = (const float*)d_in[21];
    const float* sig_w   = (const float*)d_in[22];
    const float* sig_b   = (const float*)d_in[23];
    const float* bnsig_g = (const float*)d_in[24];
    const float* bnsig_b = (const float*)d_in[25];

    unsigned short* wsp   = (unsigned short*)d_ws;
    unsigned short* wcvt  = wsp;                     // 626688
    unsigned short* upwt  = wcvt + 626688;           // 1327104
    unsigned short* y_pe  = upwt + 1327104;          // 1769472  [4608][384]
    unsigned short* s_pe  = y_pe + 1769472;          //  884736  [4608][192]
    unsigned short* y_c1  = s_pe + 884736;           // 1769472
    unsigned short* s_c2  = y_c1 + 1769472;          //  884736
    unsigned short* y_up  = s_c2 + 884736;           // 1769472
    unsigned short* QKtok = y_up + 1769472;          // 3538944  [4608][768]
    unsigned short* Vch   = QKtok + 3538944;         //  884736  [b][192][2304]
    unsigned short* Ztok  = Vch + 884736;            //  884736  [4608][192]
    float*          s_ch  = (float*)(Ztok + 884736); //  884736 fp32
    float*          qkb   = s_ch + 884736;           //  768 fp32
    float*          peY   = qkb + 768;               //  18432 fp32
    float*          peS   = peY + 18432;             //  9216 fp32

    const unsigned short* conv1wb = wcvt;
    const unsigned short* wqkb    = wcvt + 147456;   // wq||wk, 768 x 384
    const unsigned short* conv2wb = wcvt + 442368;
    const unsigned short* wvb     = wcvt + 479232;
    const unsigned short* sigwb   = wcvt + 516096;
    const unsigned short* conv3wb = wcvt + 552960;

    build_pe_kernel<<<108, 256, 0, stream>>>(peY, peS);
    prep_w_kernel<<<7632, 256, 0, stream>>>(conv1_w, wq_w, wk_w, conv2_w,
                                            wv_w, sig_w, conv3_w, wcvt,
                                            wq_b, wk_b, qkb, up_w, upwt);
    prep_pe_kernel<<<648, 256, 0, stream>>>(y, s, peY, peS, y_pe, s_pe, s_ch);

    Seg sz = {};   // unused slot filler

    // G1: up (432 blk, long pole first) + conv1 (432) + conv2 (216) -> 1080
    {
        Seg a = { y_pe, upwt, D2c, 9 * D2c, 9 * D2c, 6, 0, 432, 1,
                  up_b, nullptr, nullptr, (char*)y_up, D2c, 0 };
        Seg b = { y_pe, conv1wb, D2c, D2c, D2c, 6, 432, 432, 2,
                  conv1_b, bn1_g, bn1_b, (char*)y_c1, D2c, 0 };
        Seg c = { s_pe, conv2wb, Dc, Dc, Dc, 3, 864, 216, 2,
                  conv2_b, bn2_g, bn2_b, (char*)s_c2, Dc, 0 };
        fused_gemm<3><<<1080, 256, 0, stream>>>(a, b, c, nullptr);
    }
    // G2: QK (864) + conv3 (216) + V (216) -> 1296 blocks
    {
        Seg a = { y_c1, wqkb, D2c, D2c, D2c, 12, 0, 864, 0,
                  qkb, nullptr, nullptr, (char*)QKtok, 768, 0 };
        Seg b = { conv3wb, y_up, D2c, D2c, D2c, 72, 864, 216, 2 | 4 | 8,
                  conv3_b, bn3_g, bn3_b,
                  (char*)((float*)d_out + (long)Dc * NYc), NYc, 884736 };
        Seg c = { wvb, s_c2, Dc, Dc, Dc, 72, 1080, 216, 8,
                  wv_b, nullptr, nullptr, (char*)Vch, NYc, 442368 };
        fused_gemm<3><<<1296, 256, 0, stream>>>(a, b, c, nullptr);
    }
    // attention
    attn_kernel<<<576, 512, 0, stream>>>(QKtok, Vch, Ztok);
    // G4: sigmoid gate (216 blocks)
    {
        Seg a = { sigwb, Ztok, Dc, Dc, Dc, 72, 0, 216, 4 | 8 | 16,
                  sig_b, bnsig_g, bnsig_b, (char*)d_out, NYc, 884736 };
        fused_gemm<1><<<216, 256, 0, stream>>>(a, sz, sz, s_ch);
    }
}

// Round 7
// 187.011 us; speedup vs baseline: 1.5373x; 1.0614x over previous
//
#include <hip/hip_runtime.h>
#include <hip/hip_bf16.h>

#define Dc   192
#define D2c  384
#define NYc  2304   // 48*48

// 1/sqrt(192) * log2(e): folded into wq weights+bias so QK^T scores are in
// log2 domain and softmax uses raw v_exp_f32 (= 2^x).
#define QSCALE 0.1041175462f

typedef __attribute__((ext_vector_type(8))) short short8;
typedef __attribute__((ext_vector_type(4))) float f32x4;

__device__ __forceinline__ unsigned short f2bf(float f) {
    unsigned int u = __float_as_uint(f);
    u += 0x7FFFu + ((u >> 16) & 1u);   // RNE
    return (unsigned short)(u >> 16);
}
__device__ __forceinline__ float bf2f(unsigned short u) {
    return __uint_as_float((unsigned)u << 16);
}
__device__ __forceinline__ float fexp2(float x) {
    float r; asm("v_exp_f32 %0, %1" : "=v"(r) : "v"(x)); return r;
}
__device__ __forceinline__ unsigned cvtpk(float lo, float hi) {
    unsigned r; asm("v_cvt_pk_bf16_f32 %0, %1, %2" : "=v"(r) : "v"(lo), "v"(hi));
    return r;
}
// bijective XCD-chunk swizzle (any nwg)
__device__ __forceinline__ int swzb(int orig, int nwg) {
    int q = nwg >> 3, r = nwg & 7, x = orig & 7;
    int base = (x < r) ? x * (q + 1) : r * (q + 1) + (x - r) * q;
    return base + (orig >> 3);
}

// ---------------------------------------------------------------------------
// pe2d tables: peY[c][p] (384x48), peS[c][p] (192x48)
// ---------------------------------------------------------------------------
__global__ __launch_bounds__(256)
void build_pe_kernel(float* __restrict__ peY, float* __restrict__ peS) {
    int idx = blockIdx.x * 256 + threadIdx.x;    // 27648 total
    int c, p, C; float* dst; int off;
    if (idx < 18432) { c = idx / 48; p = idx % 48; C = 384; dst = peY; off = idx; }
    else { int k = idx - 18432; c = k / 48; p = k % 48; C = 192; dst = peS; off = k; }
    int dh = C >> 1;
    int i = ((c < dh) ? c : c - dh) >> 1;
    float divv = expf((float)(2 * i) * (-9.210340371976184f / (float)dh));
    float ang = (float)p * divv;
    dst[off] = (c & 1) ? cosf(ang) : sinf(ang);
}

// PE add + LDS-tiled transpose to token-major bf16 (y and s; s keeps fp32 ch-major)
__global__ __launch_bounds__(256)
void prep_pe_kernel(const float* __restrict__ y, const float* __restrict__ s,
                    const float* __restrict__ peY, const float* __restrict__ peS,
                    unsigned short* __restrict__ ytok, unsigned short* __restrict__ stok,
                    float* __restrict__ sch) {
    __shared__ unsigned short T[64][66];
    int bid = blockIdx.x;
    int b, ct, nt, C; const float* in; const float* pe; unsigned short* outp; bool isS;
    if (bid < 432) { isS = false; b = bid / 216; int r = bid % 216; ct = r / 36; nt = r % 36;
                     in = y; pe = peY; outp = ytok; C = 384; }
    else { int l = bid - 432; isS = true; b = l / 108; int r = l % 108; ct = r / 36; nt = r % 36;
           in = s; pe = peS; outp = stok; C = 192; }
    int t = threadIdx.x;
    int nl = t & 63;
    int n = nt * 64 + nl;
    int pos_x = n % 48, pos_y = n / 48;
    #pragma unroll
    for (int i = 0; i < 16; ++i) {
        int cl = (t >> 6) + 4 * i;
        int c = ct * 64 + cl;
        int pos = (c < (C >> 1)) ? pos_x : pos_y;
        long gi = (long)b * C * NYc + (long)c * NYc + n;
        float v = in[gi] + pe[c * 48 + pos];
        if (isS) sch[gi] = v;
        T[nl][cl] = f2bf(v);
    }
    __syncthreads();
    #pragma unroll
    for (int i = 0; i < 8; ++i) {
        int nl2 = (t >> 5) + 8 * i;
        int cp  = t & 31;
        unsigned u = (unsigned)T[nl2][2 * cp] | ((unsigned)T[nl2][2 * cp + 1] << 16);
        long row = (long)b * NYc + nt * 64 + nl2;
        *(unsigned*)(outp + row * C + ct * 64 + 2 * cp) = u;
    }
}

// weights: seven 1x1 mats bf16 (wq pre-scaled) + qk bias + up_w transpose to
// upT [j=tap*384+c][m] + c3b[o] = conv3_w[o,:]@up_b + conv3_b[o]
__global__ __launch_bounds__(256)
void prep_w_kernel(const float* __restrict__ w0, const float* __restrict__ w1,
                   const float* __restrict__ w2, const float* __restrict__ w3,
                   const float* __restrict__ w4, const float* __restrict__ w5,
                   const float* __restrict__ w6, unsigned short* __restrict__ dst,
                   const float* __restrict__ wq_b, const float* __restrict__ wk_b,
                   float* __restrict__ qkb,
                   const float* __restrict__ upw, unsigned short* __restrict__ upT,
                   const float* __restrict__ up_b, const float* __restrict__ conv3_b,
                   float* __restrict__ c3b) {
    int idx = blockIdx.x * 256 + threadIdx.x;    // 1953792 + 192
    if (idx < 626688) {
        if (idx < 768)
            qkb[idx] = (idx < 384) ? wq_b[idx] * QSCALE : wk_b[idx - 384];
        const float* src; int off; float scl = 1.0f;
        if      (idx < 147456) { src = w0; off = idx; }
        else if (idx < 294912) { src = w1; off = idx - 147456; scl = QSCALE; }
        else if (idx < 442368) { src = w2; off = idx - 294912; }
        else if (idx < 479232) { src = w3; off = idx - 442368; }
        else if (idx < 516096) { src = w4; off = idx - 479232; }
        else if (idx < 552960) { src = w5; off = idx - 516096; }
        else                   { src = w6; off = idx - 552960; }
        dst[idx] = f2bf(src[off] * scl);
    } else if (idx < 1953792) {
        int k = idx - 626688;                    // upT[j][m] = up_w[m][c][tap]
        int j = k / 384, m = k % 384;
        int tap = j / 384, c = j % 384;
        upT[k] = f2bf(upw[((long)m * 384 + c) * 9 + tap]);
    } else if (idx < 1953984) {
        int o = idx - 1953792;                   // c3b fold (w6 = conv3_w)
        float acc = 0.f;
        for (int m = 0; m < 384; ++m) acc += w6[o * 384 + m] * up_b[m];
        c3b[o] = acc + conv3_b[o];
    }
}

// ---------------------------------------------------------------------------
// Fused multi-segment bf16 MFMA GEMM. 64x64 tile, 4 waves (32x32), BK=64,
// double-buffered LDS (one barrier per K-step).
// D[m][n] = sum_k A'[m][k] * B'[n][k]; A',B' row-major [free][k] bf16.
// flags: 1=B-side im2col (3x3 SAME over token-major y_pe), 2=BN+ReLU,
//        4=f32 out, 8=ch-major out (n batch-wraps; bias axis m),
//        16=sigmoid-gate (*smul), 32=no bias.
// nSplit>1: block range covers nSplit K-chunks (A col offset g*K, im2col
// kBase g*K, out offset g*oSplitBytes).
// ---------------------------------------------------------------------------
struct Seg {
    const unsigned short* A; const unsigned short* B;
    int aP, bP, K, nT, blkOff, nBlk, flags, nSplit;
    long oSplitBytes;
    const float *bias, *bng, *bnb;
    char* out; int oPitch; long oBatch;
};

template<int NSEG>
__global__ __launch_bounds__(256)
void fused_gemm(Seg s0, Seg s1, Seg s2, const float* __restrict__ smul)
{
    int raw = blockIdx.x;
    Seg sg = s0;
    if (NSEG > 1 && raw >= s1.blkOff) sg = s1;
    if (NSEG > 2 && raw >= s2.blkOff) sg = s2;
    int local = swzb(raw - sg.blkOff, sg.nBlk);
    int kBase = 0;
    if (sg.nSplit > 1) {
        int pc = sg.nBlk / sg.nSplit;
        int g = local / pc; local -= g * pc;
        sg.A += (long)g * sg.K;
        sg.out += (long)g * sg.oSplitBytes;
        kBase = g * sg.K;
    }
    int mt = local / sg.nT, nt = local - mt * sg.nT;
    int m0 = mt * 64, n0 = nt * 64;

    __shared__ __align__(16) unsigned short As[2][64][72];
    __shared__ __align__(16) unsigned short Bs[2][64][72];

    int t = threadIdx.x, lane = t & 63, w = t >> 6;
    int lr = lane & 15, lg = lane >> 4;
    int wm = (w >> 1) * 32, wn = (w & 1) * 32;

    f32x4 acc[2][2];
    #pragma unroll
    for (int i = 0; i < 2; ++i)
        #pragma unroll
        for (int j = 0; j < 2; ++j)
            acc[i][j] = (f32x4){0.f, 0.f, 0.f, 0.f};

    uint4 ra[2], rb[2];
    bool im2colB = (sg.flags & 1) != 0;

    auto load = [&](int k0) {
        #pragma unroll
        for (int i = 0; i < 2; ++i) {
            int idx = t + i * 256, row = idx >> 3, sl = idx & 7;
            ra[i] = *(const uint4*)(sg.A + (long)(m0 + row) * sg.aP + k0 + sl * 8);
            if (im2colB) {
                int tok = n0 + row;
                int bb = tok >= NYc;
                int n = tok - bb * NYc;
                int kk = kBase + k0;
                int tap = kk / 384;
                int rem = kk - tap * 384 + sl * 8;
                int py = n / 48 + tap / 3 - 1;
                int px = n % 48 + tap % 3 - 1;
                rb[i] = (py >= 0 && py < 48 && px >= 0 && px < 48)
                    ? *(const uint4*)(sg.B + ((long)bb * NYc + py * 48 + px) * sg.bP + rem)
                    : make_uint4(0, 0, 0, 0);
            } else {
                rb[i] = *(const uint4*)(sg.B + (long)(n0 + row) * sg.bP + k0 + sl * 8);
            }
        }
    };
    auto store = [&](int buf) {
        #pragma unroll
        for (int i = 0; i < 2; ++i) {
            int idx = t + i * 256;
            *(uint4*)&As[buf][idx >> 3][(idx & 7) * 8] = ra[i];
            *(uint4*)&Bs[buf][idx >> 3][(idx & 7) * 8] = rb[i];
        }
    };

    load(0); store(0); __syncthreads();
    int NT = sg.K >> 6;
    int cur = 0;
    for (int tt = 0; tt < NT; ++tt) {
        bool more = (tt + 1 < NT);
        if (more) load((tt + 1) << 6);           // issue-early prefetch
        #pragma unroll
        for (int kk = 0; kk < 2; ++kk) {
            short8 a0 = *(const short8*)&As[cur][wm + lr][kk * 32 + lg * 8];
            short8 a1 = *(const short8*)&As[cur][wm + 16 + lr][kk * 32 + lg * 8];
            short8 b0 = *(const short8*)&Bs[cur][wn + lr][kk * 32 + lg * 8];
            short8 b1 = *(const short8*)&Bs[cur][wn + 16 + lr][kk * 32 + lg * 8];
            acc[0][0] = __builtin_amdgcn_mfma_f32_16x16x32_bf16(a0, b0, acc[0][0], 0, 0, 0);
            acc[0][1] = __builtin_amdgcn_mfma_f32_16x16x32_bf16(a0, b1, acc[0][1], 0, 0, 0);
            acc[1][0] = __builtin_amdgcn_mfma_f32_16x16x32_bf16(a1, b0, acc[1][0], 0, 0, 0);
            acc[1][1] = __builtin_amdgcn_mfma_f32_16x16x32_bf16(a1, b1, acc[1][1], 0, 0, 0);
        }
        if (more) store(cur ^ 1);                // other buffer: no pre-barrier
        __syncthreads();
        cur ^= 1;
    }

    #pragma unroll
    for (int i = 0; i < 2; ++i)
    #pragma unroll
    for (int j = 0; j < 2; ++j)
    #pragma unroll
    for (int r = 0; r < 4; ++r) {
        int gm = m0 + wm + i * 16 + lg * 4 + r;
        int gn = n0 + wn + j * 16 + lr;
        int ch = (sg.flags & 8) ? gm : gn;
        float v = acc[i][j][r];
        if (!(sg.flags & 32)) v += sg.bias[ch];
        if (sg.flags & 2)
            v = fmaxf(fmaf(v, sg.bng[ch], sg.bnb[ch]), 0.f);
        long o; int b = 0, tok = gn;
        if (sg.flags & 8) {
            b = gn >= NYc; tok = gn - b * NYc;
            o = (long)b * sg.oBatch + (long)gm * sg.oPitch + tok;
        } else {
            o = (long)gm * sg.oPitch + gn;
        }
        if (sg.flags & 16) {
            v = fmaf(v, sg.bng[ch], sg.bnb[ch]);
            v = 1.f / (1.f + __expf(-v));
            v *= smul[(long)b * 442368 + (long)gm * NYc + tok];
        }
        if (sg.flags & 4) ((float*)sg.out)[o] = v;
        else              ((unsigned short*)sg.out)[o] = f2bf(v);
    }
}

// ---------------------------------------------------------------------------
// reduce 3 bf16 split-K partials + fused bias + BN3 + ReLU -> d_out[192:384) f32
// ---------------------------------------------------------------------------
__global__ __launch_bounds__(256)
void reduce_up_kernel(const unsigned short* __restrict__ part,
                      const float* __restrict__ c3b,
                      const float* __restrict__ bn3g, const float* __restrict__ bn3b,
                      float* __restrict__ out) {
    int tid = blockIdx.x * 256 + threadIdx.x;   // 221184
    int e = tid * 4;
    int b = e / 442368; int r = e - b * 442368;
    int o = r / 2304;
    ushort4 p0 = *(const ushort4*)(part + e);
    ushort4 p1 = *(const ushort4*)(part + 884736 + e);
    ushort4 p2 = *(const ushort4*)(part + 1769472 + e);
    float g = bn3g[o], bb = bn3b[o], cb = c3b[o];
    float4 res;
    float* rp = (float*)&res;
    unsigned short* q0 = (unsigned short*)&p0;
    unsigned short* q1 = (unsigned short*)&p1;
    unsigned short* q2 = (unsigned short*)&p2;
    #pragma unroll
    for (int j = 0; j < 4; ++j) {
        float v = bf2f(q0[j]) + bf2f(q1[j]) + bf2f(q2[j]) + cb;
        rp[j] = fmaxf(fmaf(v, g, bb), 0.f);
    }
    *(float4*)(out + (long)b * 884736 + 442368 + r) = res;
}

// ---------------------------------------------------------------------------
// Fused MFMA flash attention (unchanged structure).
// ---------------------------------------------------------------------------
__global__ __launch_bounds__(512)
void attn_kernel(const unsigned short* __restrict__ QK,
                 const unsigned short* __restrict__ Vc,
                 unsigned short* __restrict__ Zt)
{
    int nid = swzb(blockIdx.x, 576);
    int qb = nid % 36;
    int bh = nid / 36;
    int b = bh >> 3, h = bh & 7;
    const unsigned short* Qg = QK + (long)b * NYc * 768 + h * 48;
    const unsigned short* Kg = Qg + 384;
    const unsigned short* Vg = Vc + ((long)b * Dc + h * 24) * NYc;
    unsigned short*       Z  = Zt + (long)b * NYc * Dc + h * 24;

    __shared__ __align__(16) unsigned short Ks_[128][72];
    __shared__ __align__(16) unsigned short Vs_[32][136];
    __shared__ __align__(16) unsigned int   Ps_[8][16][36];

    int t = threadIdx.x, lane = t & 63, w = t >> 6;
    int lr = lane & 15, lg = lane >> 4;
    int tm = w >> 1, hf = w & 1;
    int q0 = qb * 64;

    short8 z8 = {0, 0, 0, 0, 0, 0, 0, 0};
    const unsigned short* qrow = Qg + (long)(q0 + tm * 16 + lr) * 768;
    short8 bq0 = *(const short8*)(qrow + lg * 8);
    short8 bq1 = (lg < 2) ? *(const short8*)(qrow + 32 + lg * 8) : z8;

    float m_run = -1e30f, l_run = 0.f;
    f32x4 O0 = {0.f, 0.f, 0.f, 0.f}, O1 = {0.f, 0.f, 0.f, 0.f};

    for (int kt = 0; kt < 18; ++kt) {
        long k0 = kt * 128;
        #pragma unroll
        for (int i = 0; i < 2; ++i) {
            int idx = t + i * 512;
            int row = idx >> 3, sl = idx & 7;
            uint4 v = make_uint4(0, 0, 0, 0);
            if (sl < 6) v = *(const uint4*)(Kg + (k0 + row) * 768 + sl * 8);
            *(uint4*)&Ks_[row][sl * 8] = v;
        }
        if (t < 384) {
            int row = t >> 4, sl = t & 15;
            *(uint4*)&Vs_[row][sl * 8] =
                *(const uint4*)(Vg + (long)row * NYc + k0 + sl * 8);
        }
        __syncthreads();

        f32x4 sS[4];
        #pragma unroll
        for (int ks = 0; ks < 4; ++ks) {
            short8 ak0 = *(const short8*)&Ks_[hf * 64 + ks * 16 + lr][lg * 8];
            short8 ak1 = *(const short8*)&Ks_[hf * 64 + ks * 16 + lr][32 + lg * 8];
            f32x4 c = {0.f, 0.f, 0.f, 0.f};
            c = __builtin_amdgcn_mfma_f32_16x16x32_bf16(ak0, bq0, c, 0, 0, 0);
            c = __builtin_amdgcn_mfma_f32_16x16x32_bf16(ak1, bq1, c, 0, 0, 0);
            sS[ks] = c;
        }

        float tmax = -1e30f;
        #pragma unroll
        for (int ks = 0; ks < 4; ++ks)
            #pragma unroll
            for (int r = 0; r < 4; ++r) tmax = fmaxf(tmax, sS[ks][r]);
        tmax = fmaxf(tmax, __shfl_xor(tmax, 16));
        tmax = fmaxf(tmax, __shfl_xor(tmax, 32));

        if (__any(tmax > m_run + 10.f)) {
            float mn = fmaxf(m_run, tmax);
            float al = fexp2(m_run - mn);
            m_run = mn;
            l_run *= al;
            #pragma unroll
            for (int rr = 0; rr < 4; ++rr) {
                float arr = __shfl(al, (lane & 48) | (lg * 4 + rr));
                O0[rr] *= arr; O1[rr] *= arr;
            }
        }

        float psum = 0.f;
        #pragma unroll
        for (int ks = 0; ks < 4; ++ks) {
            float p0 = fexp2(sS[ks][0] - m_run);
            float p1 = fexp2(sS[ks][1] - m_run);
            float p2 = fexp2(sS[ks][2] - m_run);
            float p3 = fexp2(sS[ks][3] - m_run);
            psum += (p0 + p1) + (p2 + p3);
            Ps_[w][lr][8 * ks + 2 * lg]     = cvtpk(p0, p1);
            Ps_[w][lr][8 * ks + 2 * lg + 1] = cvtpk(p2, p3);
        }
        psum += __shfl_xor(psum, 16);
        psum += __shfl_xor(psum, 32);
        l_run += psum;

        short8 ap0 = *(const short8*)&Ps_[w][lr][4 * lg];
        short8 ap1 = *(const short8*)&Ps_[w][lr][16 + 4 * lg];
        short8 bv00 = *(const short8*)&Vs_[lr][hf * 64 + lg * 8];
        short8 bv01 = *(const short8*)&Vs_[lr][hf * 64 + 32 + lg * 8];
        short8 bv10 = *(const short8*)&Vs_[16 + lr][hf * 64 + lg * 8];
        short8 bv11 = *(const short8*)&Vs_[16 + lr][hf * 64 + 32 + lg * 8];
        O0 = __builtin_amdgcn_mfma_f32_16x16x32_bf16(ap0, bv00, O0, 0, 0, 0);
        O0 = __builtin_amdgcn_mfma_f32_16x16x32_bf16(ap1, bv01, O0, 0, 0, 0);
        O1 = __builtin_amdgcn_mfma_f32_16x16x32_bf16(ap0, bv10, O1, 0, 0, 0);
        O1 = __builtin_amdgcn_mfma_f32_16x16x32_bf16(ap1, bv11, O1, 0, 0, 0);
        __syncthreads();
    }

    float* Cf = (float*)&Ps_[0][0][0];
    float* T = Cf + tm * 576;
    if (hf == 1) {
        #pragma unroll
        for (int j = 0; j < 4; ++j) {
            T[lane * 8 + j]     = O0[j];
            T[lane * 8 + 4 + j] = O1[j];
        }
        if (lane < 16) { T[512 + lane] = m_run; T[528 + lane] = l_run; }
    }
    __syncthreads();
    if (hf == 0) {
        float mB = T[512 + lr], lB = T[528 + lr];
        float mS = fmaxf(m_run, mB);
        float aA = fexp2(m_run - mS), aB = fexp2(mB - mS);
        float invl = 1.f / (l_run * aA + lB * aB);
        float fA = aA * invl, fB = aB * invl;
        #pragma unroll
        for (int rr = 0; rr < 4; ++rr) {
            int src = (lane & 48) | (lg * 4 + rr);
            float gA = __shfl(fA, src), gB = __shfl(fB, src);
            int n = q0 + tm * 16 + lg * 4 + rr;
            unsigned short* zr = Z + (long)n * Dc;
            float z0 = O0[rr] * gA + T[lane * 8 + rr] * gB;
            zr[lr] = f2bf(z0);
            if (lr < 8) {
                float z1 = O1[rr] * gA + T[lane * 8 + 4 + rr] * gB;
                zr[16 + lr] = f2bf(z1);
            }
        }
    }
}

// ---------------------------------------------------------------------------
extern "C" void kernel_launch(void* const* d_in, const int* in_sizes, int n_in,
                              void* d_out, int out_size, void* d_ws, size_t ws_size,
                              hipStream_t stream) {
    const float* y       = (const float*)d_in[0];
    const float* s       = (const float*)d_in[1];
    const float* wq_w    = (const float*)d_in[2];
    const float* wq_b    = (const float*)d_in[3];
    const float* wk_w    = (const float*)d_in[4];
    const float* wk_b    = (const float*)d_in[5];
    const float* wv_w    = (const float*)d_in[6];
    const float* wv_b    = (const float*)d_in[7];
    const float* conv1_w = (const float*)d_in[8];
    const float* conv1_b = (const float*)d_in[9];
    const float* bn1_g   = (const float*)d_in[10];
    const float* bn1_b   = (const float*)d_in[11];
    const float* conv2_w = (const float*)d_in[12];
    const float* conv2_b = (const float*)d_in[13];
    const float* bn2_g   = (const float*)d_in[14];
    const float* bn2_b   = (const float*)d_in[15];
    const float* up_w    = (const float*)d_in[16];
    const float* up_b    = (const float*)d_in[17];
    const float* conv3_w = (const float*)d_in[18];
    const float* conv3_b = (const float*)d_in[19];
    const float* bn3_g   = (const float*)d_in[20];
    const float* bn3_b   = (const float*)d_in[21];
    const float* sig_w   = (const float*)d_in[22];
    const float* sig_b   = (const float*)d_in[23];
    const float* bnsig_g = (const float*)d_in[24];
    const float* bnsig_b = (const float*)d_in[25];

    unsigned short* wsp   = (unsigned short*)d_ws;
    unsigned short* wcvt  = wsp;                     // 626688
    unsigned short* upT   = wcvt + 626688;           // 1327104 [3456][384]
    unsigned short* Wc    = upT + 1327104;           //  663552 [192][3456]
    unsigned short* y_pe  = Wc + 663552;             // 1769472 [4608][384]
    unsigned short* s_pe  = y_pe + 1769472;          //  884736 [4608][192]
    unsigned short* y_c1  = s_pe + 884736;           // 1769472
    unsigned short* s_c2  = y_c1 + 1769472;          //  884736
    unsigned short* QKtok = s_c2 + 884736;           // 3538944 [4608][768]
    unsigned short* Vch   = QKtok + 3538944;         //  884736 [b][192][2304]
    unsigned short* partZ = Vch + 884736;            // 2654208 (partials; Ztok aliases)
    unsigned short* Ztok  = partZ;                   //  884736 (lifetime disjoint)
    float*          s_ch  = (float*)(partZ + 2654208); // 884736 fp32
    float*          qkb   = s_ch + 884736;           //  768 fp32
    float*          c3b   = qkb + 768;               //  192 fp32
    float*          peY   = c3b + 192;               //  18432 fp32
    float*          peS   = peY + 18432;             //  9216 fp32

    const unsigned short* conv1wb = wcvt;
    const unsigned short* wqkb    = wcvt + 147456;   // wq||wk, 768 x 384
    const unsigned short* conv2wb = wcvt + 442368;
    const unsigned short* wvb     = wcvt + 479232;
    const unsigned short* sigwb   = wcvt + 516096;
    const unsigned short* conv3wb = wcvt + 552960;

    build_pe_kernel<<<108, 256, 0, stream>>>(peY, peS);
    prep_w_kernel<<<7633, 256, 0, stream>>>(conv1_w, wq_w, wk_w, conv2_w,
                                            wv_w, sig_w, conv3_w, wcvt,
                                            wq_b, wk_b, qkb, up_w, upT,
                                            up_b, conv3_b, c3b);
    prep_pe_kernel<<<648, 256, 0, stream>>>(y, s, peY, peS, y_pe, s_pe, s_ch);

    Seg sz = {};

    // W' = conv3_w @ up_w : A=conv3wb [192][384], B=upT [3456][384] -> Wc [192][3456]
    {
        Seg a = { conv3wb, upT, 384, 384, 384, 54, 0, 162, 32, 1, 0,
                  nullptr, nullptr, nullptr, (char*)Wc, 3456, 0 };
        fused_gemm<1><<<162, 256, 0, stream>>>(a, sz, sz, nullptr);
    }
    // G1: combined up*conv3 split-K=3 (648) + conv1 (432) + conv2 (216) -> 1296
    {
        Seg a = { Wc, y_pe, 3456, 384, 1152, 72, 0, 648, 1 | 8 | 32, 3,
                  (long)884736 * 2,
                  nullptr, nullptr, nullptr, (char*)partZ, NYc, 442368 };
        Seg b = { y_pe, conv1wb, 384, 384, 384, 6, 648, 432, 2, 1, 0,
                  conv1_b, bn1_g, bn1_b, (char*)y_c1, 384, 0 };
        Seg c = { s_pe, conv2wb, 192, 192, 192, 3, 1080, 216, 2, 1, 0,
                  conv2_b, bn2_g, bn2_b, (char*)s_c2, 192, 0 };
        fused_gemm<3><<<1296, 256, 0, stream>>>(a, b, c, nullptr);
    }
    // G2: QK (864) + V (216) -> 1080
    {
        Seg a = { y_c1, wqkb, 384, 384, 384, 12, 0, 864, 0, 1, 0,
                  qkb, nullptr, nullptr, (char*)QKtok, 768, 0 };
        Seg b = { wvb, s_c2, 192, 192, 192, 72, 864, 216, 8, 1, 0,
                  wv_b, nullptr, nullptr, (char*)Vch, NYc, 442368 };
        fused_gemm<2><<<1080, 256, 0, stream>>>(a, b, sz, nullptr);
    }
    // reduce split-K partials -> d_out[192:384) fp32 (with bn3+relu)
    reduce_up_kernel<<<864, 256, 0, stream>>>(partZ, c3b, bn3_g, bn3_b,
                                              (float*)d_out);
    // attention
    attn_kernel<<<576, 512, 0, stream>>>(QKtok, Vch, Ztok);
    // G4: sigmoid gate (216)
    {
        Seg a = { sigwb, Ztok, 192, 192, 192, 72, 0, 216, 4 | 8 | 16, 1, 0,
                  sig_b, bnsig_g, bnsig_b, (char*)d_out, NYc, 884736 };
        fused_gemm<1><<<216, 256, 0, stream>>>(a, sz, sz, s_ch);
    }
}